// Round 1
// 251.199 us; speedup vs baseline: 1.1233x; 1.1233x over previous
//
#include <hip/hip_runtime.h>
#include <hip/hip_bf16.h>
#include <hip/hip_fp16.h>

// RecursiveNN forest bottom-up pass, fp32 in / fp32 out.
// Fused K1+K2: level 1 streams 134 MB of leaves through LDS staging into an
// LDS-resident Hbuf (128 rows = one quarter-tree frontier), then levels 2..8
// halve in place — the 67 MB H1 HBM round-trip is eliminated.
// Projection is a 4-step chained fp16 MFMA (P padded [16,128]) instead of the
// 80-thread serial 128-FMA dot chain.
// K3: top 2 levels (3 nodes/tree) in fp32, unchanged (verified).

typedef _Float16 f16_t;
typedef _Float16 f16x4 __attribute__((ext_vector_type(4)));
typedef _Float16 f16x8 __attribute__((ext_vector_type(8)));
typedef float f32x4 __attribute__((ext_vector_type(4)));

#define HSTRIDE 136   // f16 elems per row slot: 272 B, 16B-aligned

static __device__ __forceinline__ f32x4 mfma16(f16x8 a, f16x8 b, f32x4 c) {
    return __builtin_amdgcn_mfma_f32_16x16x32_f16(a, b, c, 0, 0, 0);
}

// One-shot: W [128,256] fp32 -> fp16 Wh; P [5,128] fp32 -> fp16 Ph.
__global__ void prep_kernel(const float* __restrict__ W, const float* __restrict__ P,
                            f16_t* __restrict__ Wh, f16_t* __restrict__ Ph) {
    if (blockIdx.x < 128) {
        const int i = blockIdx.x * 256 + threadIdx.x;
        Wh[i] = (f16_t)W[i];
    } else {
        for (int i = threadIdx.x; i < 640; i += 256) Ph[i] = (f16_t)P[i];
    }
}

// ---------------- fused K1+K2: levels 1..8 for one 128-row quarter-tree ----------------
__global__ __launch_bounds__(256, 2)
void forest_kernel(const float* __restrict__ leaves,
                   const f16_t* __restrict__ Wh,
                   const f16_t* __restrict__ Ph,
                   const float* __restrict__ bW,
                   const float* __restrict__ bP,
                   f16_t* __restrict__ Q,          // [1024,128] quarter roots
                   float* __restrict__ out)
{
    __shared__ f16_t Stg[2][32 * HSTRIDE];       // 17408 B leaf staging dbuf
    __shared__ f16_t Hbuf[128 * HSTRIDE];        // 34816 B frontier, in-place halving

    const int tid   = threadIdx.x;
    const int wave  = tid >> 6;
    const int lane  = tid & 63;
    const int mlane = lane & 15;
    const int q     = lane >> 4;
    const int tree  = blockIdx.x >> 2;
    const int qq    = blockIdx.x & 3;
    const size_t m0 = (size_t)blockIdx.x * 128;  // global level-1 pair-row base
    const float* leafbase = leaves + (size_t)blockIdx.x * 32768;

    // W b-frags (gemm_bt, verified): lane holds W[col][k*32 + q*8 + e]
    f16x8 wh[2][8];
    float bwv[2];
    #pragma unroll
    for (int n = 0; n < 2; ++n) {
        const int col = wave * 32 + n * 16 + mlane;
        bwv[n] = bW[col];
        #pragma unroll
        for (int k = 0; k < 8; ++k)
            wh[n][k] = *(const f16x8*)&Wh[col * 256 + k * 32 + q * 8];
    }

    // P b-frags, N padded 5->16 (zero rows for mlane>=5)
    f16x8 pb[4] = {};
    if (mlane < 5) {
        #pragma unroll
        for (int kb = 0; kb < 4; ++kb)
            pb[kb] = *(const f16x8*)&Ph[mlane * 128 + kb * 32 + q * 8];
    }
    const float bpv = (mlane < 5) ? bP[mlane] : 0.f;

    // proj of Hbuf rows [hrow0, hrow0+16) via 4 chained MFMAs; wave 0 calls this.
    auto proj_store = [&](int hrow0, size_t orow0, int valid) {
        f32x4 pc = {};
        #pragma unroll
        for (int kb = 0; kb < 4; ++kb) {
            const f16x8 ha = *(const f16x8*)&Hbuf[(hrow0 + mlane) * HSTRIDE + kb * 32 + q * 8];
            pc = mfma16(ha, pb[kb], pc);
        }
        if (mlane < 5) {
            #pragma unroll
            for (int r = 0; r < 4; ++r) {
                const int row = q * 4 + r;       // D layout: row=q*4+r, col=mlane (verified)
                if (row < valid) out[(orow0 + row) * 5 + mlane] = pc[r] + bpv;
            }
        }
    };

    auto store_stage = [&](int buf, const float4* pf) {
        #pragma unroll
        for (int r = 0; r < 4; ++r) {
            const int idx = tid + r * 256;       // 1024 float4 chunks = 32 leaf rows
            const int row = idx >> 5;
            const int c4  = idx & 31;
            f16x4 t4 = { (f16_t)pf[r].x, (f16_t)pf[r].y, (f16_t)pf[r].z, (f16_t)pf[r].w };
            *(f16x4*)&Stg[buf][row * HSTRIDE + c4 * 4] = t4;
        }
    };

    // ---- phase 1: level 1, 8 chunks of 16 pair-rows; H -> Hbuf (LDS) ----
    float4 pf[4];
    #pragma unroll
    for (int r = 0; r < 4; ++r) pf[r] = ((const float4*)leafbase)[tid + r * 256];
    store_stage(0, pf);

    for (int c = 0; c < 8; ++c) {
        __syncthreads();                         // Stg[c&1] visible
        if (c < 7) {
            #pragma unroll
            for (int r = 0; r < 4; ++r)
                pf[r] = ((const float4*)leafbase)[(c + 1) * 1024 + tid + r * 256];
        }
        // A-frags from pair-rows (verified pattern)
        f16x8 af[8];
        const f16_t* sb = Stg[c & 1];
        #pragma unroll
        for (int k = 0; k < 8; ++k) {
            const int off  = k * 64 + q * 16;    // byte offset in 512B pair-row
            const int trow = off >> 8;
            const int ce   = (off & 255) >> 1;
            af[k] = *(const f16x8*)&sb[(2 * mlane + trow) * HSTRIDE + ce];
        }
        f32x4 acc0 = {}, acc1 = {};
        #pragma unroll
        for (int k = 0; k < 8; ++k) {
            acc0 = mfma16(af[k], wh[0][k], acc0);
            acc1 = mfma16(af[k], wh[1][k], acc1);
        }
        if (c < 7) store_stage((c + 1) & 1, pf);

        // bias + relu -> Hbuf rows [c*16, c*16+16)  (C-layout: col=lane&15, row=q*4+r)
        #pragma unroll
        for (int r = 0; r < 4; ++r) {
            float v0 = fmaxf(acc0[r] + bwv[0], 0.f);
            float v1 = fmaxf(acc1[r] + bwv[1], 0.f);
            Hbuf[(c * 16 + q * 4 + r) * HSTRIDE + wave * 32 + mlane]      = (f16_t)v0;
            Hbuf[(c * 16 + q * 4 + r) * HSTRIDE + wave * 32 + 16 + mlane] = (f16_t)v1;
        }
        __syncthreads();                         // Hbuf chunk complete

        if (wave == 0) proj_store(c * 16, m0 + c * 16, 16);
        // next-chunk writes go to rows (c+1)*16 — disjoint from proj reads; the
        // loop-top barrier orders Stg staging behind this wave's proj anyway.
    }

    // ---- phase 2: levels 2..8, in-place LDS halving (verified K2 structure) ----
    int Mprev = 128;
    #pragma unroll 1
    for (int j = 2; j <= 8; ++j) {
        const int Mnew   = Mprev >> 1;
        const int chunks = (Mnew + 15) >> 4;
        const size_t off_j = 256 * (1024 - (2048 >> j));
        for (int c = 0; c < chunks; ++c) {
            f16x8 af[8];
            #pragma unroll
            for (int k = 0; k < 8; ++k) {
                const int off  = k * 64 + q * 16;
                const int trow = off >> 8;
                const int ce   = (off & 255) >> 1;
                af[k] = *(const f16x8*)&Hbuf[(32 * c + 2 * mlane + trow) * HSTRIDE + ce];
            }
            __syncthreads();                     // all reads done before writes
            f32x4 acc0 = {}, acc1 = {};
            #pragma unroll
            for (int k = 0; k < 8; ++k) {
                acc0 = mfma16(af[k], wh[0][k], acc0);
                acc1 = mfma16(af[k], wh[1][k], acc1);
            }
            #pragma unroll
            for (int r = 0; r < 4; ++r) {
                float v0 = fmaxf(acc0[r] + bwv[0], 0.f);
                float v1 = fmaxf(acc1[r] + bwv[1], 0.f);
                Hbuf[(c * 16 + q * 4 + r) * HSTRIDE + wave * 32 + mlane]      = (f16_t)v0;
                Hbuf[(c * 16 + q * 4 + r) * HSTRIDE + wave * 32 + 16 + mlane] = (f16_t)v1;
            }
            __syncthreads();                     // writes visible for proj / next reads

            const int valid = (Mnew - c * 16 < 16) ? (Mnew - c * 16) : 16;
            if (wave == 0)
                proj_store(c * 16,
                           off_j + (size_t)tree * (Mnew * 4) + (size_t)qq * Mnew + c * 16,
                           valid);
        }
        Mprev = Mnew;
    }

    if (tid < 16)
        *(uint4*)&Q[(size_t)blockIdx.x * 128 + tid * 8] = *(const uint4*)&Hbuf[tid * 8];
}

// ---------------- K3: top 2 levels, fp32 (verified) ----------------
__global__ __launch_bounds__(128, 4)
void rnn_top_kernel(const f16_t* __restrict__ Q,
                    const float* __restrict__ W,
                    const float* __restrict__ bW,
                    const float* __restrict__ P,
                    const float* __restrict__ bP,
                    float* __restrict__ out)
{
    __shared__ float qs[512];
    __shared__ float hs[384];
    const int t    = threadIdx.x;
    const int tree = blockIdx.x;

    #pragma unroll
    for (int i = 0; i < 4; ++i)
        qs[t + i * 128] = (float)Q[(size_t)tree * 512 + t + i * 128];
    __syncthreads();

    const float* wr = W + t * 256;
    float s0 = bW[t], s1 = s0;
    for (int k = 0; k < 256; k += 4) {
        const float4 wv = *(const float4*)(wr + k);
        s0 += wv.x * qs[k]     + wv.y * qs[k + 1]     + wv.z * qs[k + 2]     + wv.w * qs[k + 3];
        s1 += wv.x * qs[256+k] + wv.y * qs[256+k + 1] + wv.z * qs[256+k + 2] + wv.w * qs[256+k + 3];
    }
    hs[t]       = fmaxf(s0, 0.f);
    hs[128 + t] = fmaxf(s1, 0.f);
    __syncthreads();

    float s2 = bW[t];
    for (int k = 0; k < 256; k += 4) {
        const float4 wv = *(const float4*)(wr + k);
        s2 += wv.x * hs[k] + wv.y * hs[k + 1] + wv.z * hs[k + 2] + wv.w * hs[k + 3];
    }
    hs[256 + t] = fmaxf(s2, 0.f);
    __syncthreads();

    if (t < 15) {
        const int node = t / 5, c = t % 5;
        float s = bP[c];
        for (int k = 0; k < 128; ++k) s += hs[node * 128 + k] * P[c * 128 + k];
        const size_t row = (node < 2) ? (261120 + (size_t)tree * 2 + node)
                                      : (261632 + (size_t)tree);
        out[row * 5 + c] = s;
    }
}

extern "C" void kernel_launch(void* const* d_in, const int* in_sizes, int n_in,
                              void* d_out, int out_size, void* d_ws, size_t ws_size,
                              hipStream_t stream) {
    const float* leaves = (const float*)d_in[0];   // [256,1024,128] fp32
    const float* W      = (const float*)d_in[1];   // [128,256] fp32
    const float* bW     = (const float*)d_in[2];   // [128] fp32
    const float* P      = (const float*)d_in[3];   // [5,128] fp32
    const float* bP     = (const float*)d_in[4];   // [5] fp32
    float* out = (float*)d_out;                    // [256*1023, 5] fp32

    // ws layout (f16 elems): Wh 32768 | Ph 1024 | Q 131072  (~330 KB; H1 eliminated)
    f16_t* Wh = (f16_t*)d_ws;
    f16_t* Ph = Wh + 32768;
    f16_t* Q  = Wh + 32768 + 1024;

    prep_kernel<<<dim3(129), dim3(256), 0, stream>>>(W, P, Wh, Ph);
    forest_kernel<<<dim3(1024), dim3(256), 0, stream>>>(leaves, Wh, Ph, bW, bP, Q, out);
    rnn_top_kernel<<<dim3(256), dim3(128), 0, stream>>>(Q, W, bW, P, bP, out);
}